// Round 1
// 648.874 us; speedup vs baseline: 1.0998x; 1.0998x over previous
//
#include <hip/hip_runtime.h>

// ---------------------------------------------------------------------------
// MambaBlock on MI355X (gfx950).  Pipeline:
//   1. rmsnorm         : x f32 (8192x1024) -> xnorm bf16
//   2. weight packs    : W_in, [W_dt;W_B;W_C;pad] (2176x2048), W_out -> bf16;
//                        A2 = -exp(A_log)*log2(e)
//   3. gemm256<2>      : xnorm @ W_in^T -> x_inner bf16 | silu(res) bf16
//   4. conv_silu       : depthwise causal K=4 + silu -> xconv bf16
//   5. gemm256<1>      : xconv @ [Wdt;WB;WC]^T -> dt f32 (softplus) | bc f32
//   6. scan            : chunked two-pass associative scan, channel-per-lane
//   7. gemm<PLAIN>     : y @ W_out^T -> d_out f32
// R6: GEMM1/GEMM2 ported to the 256x256/BK=64 8-wave 8-phase template
// (T2 swizzle + T3/T4 counted vmcnt + T5 setprio).  R5 PMC: MfmaUtil 15.5%,
// VALUBusy 58.7%, HBM 10% -> schedule-bound (2-barrier vmcnt(0) drain per
// 32-K-step).  New schedule: per K-tile(64) 4 quadrant phases x16 MFMA,
// next-tile global_load_lds spread 2/phase, single s_waitcnt vmcnt(2) per
// K-tile (never 0 in main loop).  LDS: linear dest + inverse-swizzled global
// source + swizzled ds_read (rule 21, involution byte^((row&7)<<4)).
// GEMM2 N padded to 9 tiles (2304); pad tile clamps B rows to zero row 2175.
// Workspace: 173.625 MiB; chunk state (8.5 MB) aliases dead wdtbcb region.
// ---------------------------------------------------------------------------

typedef __bf16 bf16;
typedef __attribute__((ext_vector_type(8))) __bf16 bf16x8;
typedef __attribute__((ext_vector_type(4))) float f32x4;

#define DIM   1024
#define STATE 16
#define INNER 2048
#define BATCH 4
#define SEQ   2048
#define ROWS  (BATCH * SEQ)      // 8192
#define N1    (2 * INNER)        // 4096 (GEMM1 N)
#define NBC   2176               // 2048 dt + 16 B + 16 C + 96 pad
#define CHUNK 128                // scan chunk length
#define NC    (SEQ / CHUNK)      // 16 chunks per sequence
#define PF2   4                  // scan prefetch depth (rows)

// async global->LDS, 16 bytes per lane (lane-contiguous LDS dest)
#define GLOAD_LDS16(g, l)                                                  \
  __builtin_amdgcn_global_load_lds(                                        \
      (const __attribute__((address_space(1))) unsigned int*)(g),          \
      (__attribute__((address_space(3))) unsigned int*)(l), 16, 0, 0)

// ---------------------------------------------------------------------------
// 0. workspace-too-small diagnostic
// ---------------------------------------------------------------------------
__global__ void ws_report_kernel(float* out, float wssz, float need) {
  if (threadIdx.x == 0) { out[0] = wssz; out[1] = need; }
}

// ---------------------------------------------------------------------------
// 1. RMSNorm: one block per row (1024 floats), 256 threads x float4
// ---------------------------------------------------------------------------
__global__ __launch_bounds__(256) void rmsnorm_kernel(
    const float* __restrict__ x, const float* __restrict__ w,
    bf16* __restrict__ out) {
  const int row = blockIdx.x;
  const int t = threadIdx.x;
  const float4 v = ((const float4*)(x + (long)row * DIM))[t];
  float ss = v.x * v.x + v.y * v.y + v.z * v.z + v.w * v.w;
#pragma unroll
  for (int off = 32; off > 0; off >>= 1) ss += __shfl_xor(ss, off, 64);
  __shared__ float red[4];
  if ((t & 63) == 0) red[t >> 6] = ss;
  __syncthreads();
  const float tot = red[0] + red[1] + red[2] + red[3];
  const float scale = rsqrtf(tot * (1.0f / DIM) + 1e-6f);
  const float4 wv = ((const float4*)w)[t];
  bf16* o = out + (long)row * DIM + t * 4;
  o[0] = (bf16)(v.x * scale * wv.x);
  o[1] = (bf16)(v.y * scale * wv.y);
  o[2] = (bf16)(v.z * scale * wv.z);
  o[3] = (bf16)(v.w * scale * wv.w);
}

// ---------------------------------------------------------------------------
// 2. weight packs
// ---------------------------------------------------------------------------
__global__ __launch_bounds__(256) void cvt_bf16_kernel(
    const float* __restrict__ src, bf16* __restrict__ dst, int n) {
  const int i = blockIdx.x * 256 + threadIdx.x;
  if (i < n) dst[i] = (bf16)src[i];
}

__global__ __launch_bounds__(256) void build_wdtbc_kernel(
    const float* __restrict__ Wdt, const float* __restrict__ WB,
    const float* __restrict__ WC, bf16* __restrict__ dst) {
  const long i = (long)blockIdx.x * 256 + threadIdx.x;  // < NBC*INNER
  const long r = i >> 11;  // / INNER
  const long k = i & (INNER - 1);
  float v = 0.0f;
  if (r < 2048) v = Wdt[r * INNER + k];
  else if (r < 2064) v = WB[(r - 2048) * INNER + k];
  else if (r < 2080) v = WC[(r - 2064) * INNER + k];
  dst[i] = (bf16)v;
}

__global__ __launch_bounds__(256) void build_a2_kernel(
    const float* __restrict__ A_log, float* __restrict__ A2) {
  const int i = blockIdx.x * 256 + threadIdx.x;  // < INNER*STATE
  A2[i] = -__expf(A_log[i]) * 1.4426950408889634f;  // A * log2(e)
}

// ---------------------------------------------------------------------------
// 3/5. GEMM 256x256 8-phase: C[M,N] = A[M,K] @ B[N,K]^T  (bf16, f32 acc)
// 512 threads = 8 waves (2M x 4N); per-wave 128x64 out (8x4 16x16 frags).
// BK=64, LDS 2 x (A 32K | B 32K), K-tile double buffer.  Per K-tile: 4
// quadrant phases {ds_read frags | 2x global_load_lds next tile | barrier |
// lgkmcnt(0) | setprio(1) 16 MFMA setprio(0) | barrier}; one counted
// s_waitcnt vmcnt(2) per K-tile (vmcnt(0) only on last).  T2 swizzle:
// LDS dest linear, global source col byte ^= ((ldsrow&7)<<4), ds_read same
// XOR (involution) -> 64 lanes cover all 32 banks on b128 frag reads.
// EPI 1: col0<2048 -> softplus(acc+bias) -> Cf (stride 2048); pad tile ->
//        cols 2048..2079 -> Cf2 (stride 32), rest discarded
// EPI 2: col0<2048 -> bf16 -> Cb; else silu -> Cb2 (both stride 2048)
// ---------------------------------------------------------------------------
#define MFMA_PHASE(I0, N0)                                                    \
  __builtin_amdgcn_s_barrier();                                               \
  asm volatile("s_waitcnt lgkmcnt(0)" ::: "memory");                          \
  __builtin_amdgcn_s_setprio(1);                                              \
  _Pragma("unroll") for (int i_ = 0; i_ < 4; ++i_)                            \
  _Pragma("unroll") for (int n_ = 0; n_ < 2; ++n_)                            \
  _Pragma("unroll") for (int k_ = 0; k_ < 2; ++k_)                            \
      acc[(I0) + i_][(N0) + n_] = __builtin_amdgcn_mfma_f32_16x16x32_bf16(    \
          afr[i_][k_], bfr[(N0) + n_][k_], acc[(I0) + i_][(N0) + n_], 0, 0,   \
          0);                                                                 \
  __builtin_amdgcn_s_setprio(0);                                              \
  __builtin_amdgcn_s_barrier();

template <int EPI, int K, int NX>
__global__ __launch_bounds__(512, 2) void gemm256_kernel(
    const bf16* __restrict__ A, const bf16* __restrict__ B,
    float* __restrict__ Cf, float* __restrict__ Cf2,
    bf16* __restrict__ Cb, bf16* __restrict__ Cb2,
    const float* __restrict__ bias, int Bmax) {
  __shared__ __align__(16) char lds[2][65536];  // [buf][A 32K | B 32K]
  const int tid = threadIdx.x;
  const int lane = tid & 63;
  const int wave = tid >> 6;
  const int wm = wave >> 2;  // 0..1: M half (128 rows)
  const int wn = wave & 3;   // 0..3: N quarter (64 cols)

  // XCD-band swizzle (grid % 8 == 0): contiguous row-tile band per XCD.
  const int per = gridDim.x >> 3;
  const int lin = (blockIdx.x & 7) * per + (blockIdx.x >> 3);
  const int row_t = lin / NX;
  const int col_t = lin - row_t * NX;
  const long row0 = (long)row_t * 256;
  const long col0 = (long)col_t * 256;

  // ---- staging addressing: 512 lanes x 16B = one 64-row (128B) chunk ----
  const int srow = tid >> 3;       // lds row within 64-row chunk
  const int scb = (tid & 7) * 16;  // byte col within 128B row (linear dest)
  const int sswz = scb ^ ((srow & 7) << 4);  // inverse-swizzled source col
  const char* gA = (const char*)A + (row0 + srow) * (long)(2 * K) + sswz;
  const char* gB = (const char*)B + sswz;
  long brow[4];
#pragma unroll
  for (int q = 0; q < 4; ++q) {
    long r = col0 + q * 64 + srow;
    brow[q] = (r > (long)Bmax ? (long)Bmax : r) * (long)(2 * K);
  }

#define STG_A(bb, q, kbyte)                                                   \
  GLOAD_LDS16(gA + (long)(q) * 64 * (2 * K) + (kbyte),                        \
              lds[bb] + (q) * 8192 + srow * 128 + scb)
#define STG_B(bb, q, kbyte)                                                   \
  GLOAD_LDS16(gB + brow[q] + (kbyte),                                         \
              lds[bb] + 32768 + (q) * 8192 + srow * 128 + scb)

  // ---- fragment read addressing (swizzled) ----
  const int fm = lane & 15;
  const int fq = lane >> 4;
  const int swz = (fm & 7) << 4;
  const int ck0 = (fq * 16) ^ swz;        // kk=0 byte col
  const int ck1 = (fq * 16 + 64) ^ swz;   // kk=1 byte col
  const int aro = (wm * 128 + fm) * 128;  // byte row offset in A region
  const int bro = (wn * 64 + fm) * 128;   // byte row offset in B region

  f32x4 acc[8][4];
#pragma unroll
  for (int i = 0; i < 8; ++i)
#pragma unroll
    for (int n = 0; n < 4; ++n) acc[i][n] = (f32x4){0.f, 0.f, 0.f, 0.f};
  bf16x8 afr[4][2], bfr[4][2];

  const int NT = K / 64;
  // prologue: stage tile 0 -> buf 0 (8 issues)
#pragma unroll
  for (int q = 0; q < 4; ++q) STG_A(0, q, 0);
#pragma unroll
  for (int q = 0; q < 4; ++q) STG_B(0, q, 0);

  for (int t = 0; t < NT; ++t) {
    const int c = t & 1;
    const int nb = c ^ 1;
    const char* Ac = lds[c];
    const char* Bc = lds[c] + 32768;
    const long kb = (long)(t + 1) * 128;  // next K-tile byte offset
    const bool nx = (t + 1 < NT);
    if (nx) {
      STG_A(nb, 0, kb);
      STG_A(nb, 1, kb);
      asm volatile("s_waitcnt vmcnt(2)" ::: "memory");  // tile t landed
    } else {
      asm volatile("s_waitcnt vmcnt(0)" ::: "memory");
    }
    __builtin_amdgcn_s_barrier();
    asm volatile("" ::: "memory");  // keep ds_reads below the barrier
    // ---- phase 1: read A-low + B-low; stage A q2,q3; MFMA Q(lo, n0-1) ----
#pragma unroll
    for (int i = 0; i < 4; ++i) {
      afr[i][0] = *(const bf16x8*)(Ac + aro + i * 2048 + ck0);
      afr[i][1] = *(const bf16x8*)(Ac + aro + i * 2048 + ck1);
    }
#pragma unroll
    for (int n = 0; n < 2; ++n) {
      bfr[n][0] = *(const bf16x8*)(Bc + bro + n * 2048 + ck0);
      bfr[n][1] = *(const bf16x8*)(Bc + bro + n * 2048 + ck1);
    }
    if (nx) { STG_A(nb, 2, kb); STG_A(nb, 3, kb); }
    MFMA_PHASE(0, 0)
    // ---- phase 2: read B-high; stage B q0,q1; MFMA Q(lo, n2-3) ----
#pragma unroll
    for (int n = 2; n < 4; ++n) {
      bfr[n][0] = *(const bf16x8*)(Bc + bro + n * 2048 + ck0);
      bfr[n][1] = *(const bf16x8*)(Bc + bro + n * 2048 + ck1);
    }
    if (nx) { STG_B(nb, 0, kb); STG_B(nb, 1, kb); }
    MFMA_PHASE(0, 2)
    // ---- phase 3: read A-high; stage B q2,q3; MFMA Q(hi, n2-3) ----
#pragma unroll
    for (int i = 0; i < 4; ++i) {
      afr[i][0] = *(const bf16x8*)(Ac + aro + 8192 + i * 2048 + ck0);
      afr[i][1] = *(const bf16x8*)(Ac + aro + 8192 + i * 2048 + ck1);
    }
    if (nx) { STG_B(nb, 2, kb); STG_B(nb, 3, kb); }
    MFMA_PHASE(4, 2)
    // ---- phase 4: no reads (A-high + B-low live); MFMA Q(hi, n0-1) ----
    __builtin_amdgcn_s_setprio(1);
#pragma unroll
    for (int i = 0; i < 4; ++i)
#pragma unroll
      for (int n = 0; n < 2; ++n)
#pragma unroll
        for (int kk = 0; kk < 2; ++kk)
          acc[4 + i][n] = __builtin_amdgcn_mfma_f32_16x16x32_bf16(
              afr[i][kk], bfr[n][kk], acc[4 + i][n], 0, 0, 0);
    __builtin_amdgcn_s_setprio(0);
    __builtin_amdgcn_s_barrier();
    asm volatile("" ::: "memory");  // iter boundary: stages stay below
  }
#undef STG_A
#undef STG_B

  // epilogue: C/D layout col=lane&15, row=(lane>>4)*4+reg  [m89/m91]
  const int er = fq * 4;
  const long rbase = row0 + wm * 128;
  const long cbase = col0 + wn * 64;
  if (EPI == 2) {
    if (col0 < 2048) {
#pragma unroll
      for (int i = 0; i < 8; ++i)
#pragma unroll
        for (int n = 0; n < 4; ++n) {
          const long col = cbase + n * 16 + fm;
          const long rw = rbase + i * 16 + er;
#pragma unroll
          for (int r = 0; r < 4; ++r)
            Cb[(rw + r) * 2048 + col] = (bf16)acc[i][n][r];
        }
    } else {
#pragma unroll
      for (int i = 0; i < 8; ++i)
#pragma unroll
        for (int n = 0; n < 4; ++n) {
          const long col = cbase + n * 16 + fm - 2048;
          const long rw = rbase + i * 16 + er;
#pragma unroll
          for (int r = 0; r < 4; ++r) {
            const float v = acc[i][n][r];
            const float s = v / (1.0f + __expf(-v));
            Cb2[(rw + r) * 2048 + col] = (bf16)s;
          }
        }
    }
  } else {  // EPI == 1
    if (col0 < 2048) {
#pragma unroll
      for (int i = 0; i < 8; ++i)
#pragma unroll
        for (int n = 0; n < 4; ++n) {
          const long col = cbase + n * 16 + fm;
          const float bs = bias[col];
          const long rw = rbase + i * 16 + er;
#pragma unroll
          for (int r = 0; r < 4; ++r) {
            float z = acc[i][n][r] + bs;
            z = (z > 20.0f) ? z : log1pf(__expf(z));
            Cf[(rw + r) * 2048 + col] = z;
          }
        }
    } else if (wn == 0) {  // pad tile: cols 2048..2079 -> bc (stride 32)
#pragma unroll
      for (int i = 0; i < 8; ++i)
#pragma unroll
        for (int n = 0; n < 2; ++n) {
          const long col = n * 16 + fm;  // cbase-2048 == 0 for wn==0
          const long rw = rbase + i * 16 + er;
#pragma unroll
          for (int r = 0; r < 4; ++r)
            Cf2[(rw + r) * 32 + col] = acc[i][n][r];
        }
    }
  }
}

// ---------------------------------------------------------------------------
// 7. GEMM3 (unchanged m97 structure): C[M,N] = A[M,K] @ B[N,K]^T, plain f32
// ---------------------------------------------------------------------------
template <int EPI>
__global__ __launch_bounds__(256) void gemm_bf16_kernel(
    const bf16* __restrict__ A, const bf16* __restrict__ B,
    float* __restrict__ Cf, float* __restrict__ Cf2,
    bf16* __restrict__ Cb, bf16* __restrict__ Cb2,
    const float* __restrict__ bias, int nx, int N, int K) {
  __shared__ __align__(16) bf16 As[128 * 32];
  __shared__ __align__(16) bf16 Bs[128 * 32];
  const int tid = threadIdx.x;
  const int lane = tid & 63;
  const int wave = tid >> 6;

  const int per = gridDim.x >> 3;
  const int lin = (blockIdx.x & 7) * per + (blockIdx.x >> 3);
  const int row_t = lin / nx;
  const int col_t = lin - row_t * nx;
  const long row0 = (long)row_t * 128;
  const long col0 = (long)col_t * 128;

  const int wr = (wave >> 1) * 64;
  const int wc = (wave & 1) * 64;

  f32x4 acc[4][4];
#pragma unroll
  for (int i = 0; i < 4; i++)
#pragma unroll
    for (int j = 0; j < 4; j++) acc[i][j] = (f32x4){0.f, 0.f, 0.f, 0.f};

  const int srow = tid >> 2;
  const int scol = (tid & 3) * 8;
  const bf16* gA0 = A + (row0 + srow) * (long)K + scol;
  const bf16* gA1 = A + (row0 + srow + 64) * (long)K + scol;
  const bf16* gB0 = B + (col0 + srow) * (long)K + scol;
  const bf16* gB1 = B + (col0 + srow + 64) * (long)K + scol;
  bf16* lA0 = As + wave * 512 + lane * 8;
  bf16* lA1 = As + 64 * 32 + wave * 512 + lane * 8;
  bf16* lB0 = Bs + wave * 512 + lane * 8;
  bf16* lB1 = Bs + 64 * 32 + wave * 512 + lane * 8;

  const int fm = lane & 15;
  const int fk = (lane >> 4) * 8;

  for (int k0 = 0; k0 < K; k0 += 32) {
    GLOAD_LDS16(gA0 + k0, lA0);
    GLOAD_LDS16(gA1 + k0, lA1);
    GLOAD_LDS16(gB0 + k0, lB0);
    GLOAD_LDS16(gB1 + k0, lB1);
    __syncthreads();
    bf16x8 af[4], bfv[4];
#pragma unroll
    for (int i = 0; i < 4; i++)
      af[i] = *(const bf16x8*)(As + (wr + i * 16 + fm) * 32 + fk);
#pragma unroll
    for (int j = 0; j < 4; j++)
      bfv[j] = *(const bf16x8*)(Bs + (wc + j * 16 + fm) * 32 + fk);
#pragma unroll
    for (int i = 0; i < 4; i++)
#pragma unroll
      for (int j = 0; j < 4; j++)
        acc[i][j] = __builtin_amdgcn_mfma_f32_16x16x32_bf16(
            af[i], bfv[j], acc[i][j], 0, 0, 0);
    __syncthreads();
  }

  const int er = (lane >> 4) * 4;
  const int ec = lane & 15;
#pragma unroll
  for (int i = 0; i < 4; i++) {
#pragma unroll
    for (int j = 0; j < 4; j++) {
      const long col = col0 + wc + j * 16 + ec;
      const long rw = row0 + wr + i * 16 + er;
#pragma unroll
      for (int r = 0; r < 4; r++) {
        const float v = acc[i][j][r];
        const long row = rw + r;
        if (EPI == 0) {
          Cf[row * (long)N + col] = v;
        } else if (EPI == 1) {
          if (col0 < 2048) {
            float z = v + bias[col];
            z = (z > 20.0f) ? z : log1pf(__expf(z));
            Cf[row * 2048 + col] = z;
          } else if (col < 2080) {
            Cf2[row * 32 + (col - 2048)] = v;
          }
        } else {  // EPI == 2
          if (col0 < 2048) {
            Cb[row * 2048 + col] = (bf16)v;
          } else {
            const float s = v / (1.0f + __expf(-v));
            Cb2[row * 2048 + (col - 2048)] = (bf16)s;
          }
        }
      }
    }
  }
}

// ---------------------------------------------------------------------------
// 4. depthwise causal conv (K=4) + silu.  xin: ROWS x 2048 bf16
// ---------------------------------------------------------------------------
__global__ __launch_bounds__(256) void conv_silu_kernel(
    const bf16* __restrict__ xin, const float* __restrict__ conv_w,
    const float* __restrict__ conv_b, bf16* __restrict__ xc16) {
  const int c = blockIdx.x * 256 + threadIdx.x;  // channel 0..2047
  const int r = blockIdx.y;                      // global row 0..8191
  const int l = r & (SEQ - 1);                   // position within sequence
  const float4 w = *(const float4*)(conv_w + c * 4);
  float acc = conv_b[c];
#pragma unroll
  for (int j = 0; j < 4; j++) {
    const int lp = l - 3 + j;
    const float xv = (lp >= 0) ? (float)xin[(long)(r - 3 + j) * INNER + c] : 0.0f;
    acc += xv * ((const float*)&w)[j];
  }
  const float s = acc / (1.0f + __expf(-acc));  // silu
  xc16[(long)r * INNER + c] = (bf16)s;
}

// ---------------------------------------------------------------------------
// 6a. scan pass 1: per-chunk zero-init scan -> h_end0[16] + dt-sum.
// ---------------------------------------------------------------------------
__global__ __launch_bounds__(256) void scan_pass1_kernel(
    const float* __restrict__ dtm, const float* __restrict__ bc,
    const bf16* __restrict__ xc, const float* __restrict__ A2,
    float* __restrict__ hend, float* __restrict__ dtsum) {
  const int ch = blockIdx.x * 256 + threadIdx.x;
  const int c = blockIdx.y;
  const int b = blockIdx.z;
  const long row0 = (long)b * SEQ + (long)c * CHUNK;

  float a2[16];
#pragma unroll
  for (int q = 0; q < 4; q++) {
    const float4 t = ((const float4*)(A2 + (long)ch * 16))[q];
    a2[q * 4 + 0] = t.x; a2[q * 4 + 1] = t.y;
    a2[q * 4 + 2] = t.z; a2[q * 4 + 3] = t.w;
  }
  float h[16];
#pragma unroll
  for (int s = 0; s < 16; s++) h[s] = 0.0f;
  float dts = 0.0f;

  float dtq[PF2], xcq[PF2];
#pragma unroll
  for (int p = 0; p < PF2; p++) {
    const long r2 = row0 + p;
    dtq[p] = dtm[r2 * INNER + ch];
    xcq[p] = (float)xc[r2 * INNER + ch];
  }
  for (int l0 = 0; l0 <= CHUNK - 2 * PF2; l0 += PF2) {
#pragma unroll
    for (int p = 0; p < PF2; p++) {
      const float dt = dtq[p], xcv = xcq[p];
      const long rp = row0 + l0 + p + PF2;
      dtq[p] = dtm[rp * INNER + ch];
      xcq[p] = (float)xc[rp * INNER + ch];
      const long r = row0 + l0 + p;
      float Bv[16];
#pragma unroll
      for (int k = 0; k < 16; k++) Bv[k] = bc[r * 32 + k];
      dts += dt;
      const float u = dt * xcv;
#pragma unroll
      for (int s = 0; s < 16; s++)
        h[s] = exp2f(a2[s] * dt) * h[s] + Bv[s] * u;
    }
  }
#pragma unroll
  for (int p = 0; p < PF2; p++) {
    const float dt = dtq[p], xcv = xcq[p];
    const long r = row0 + CHUNK - PF2 + p;
    float Bv[16];
#pragma unroll
    for (int k = 0; k < 16; k++) Bv[k] = bc[r * 32 + k];
    dts += dt;
    const float u = dt * xcv;
#pragma unroll
    for (int s = 0; s < 16; s++)
      h[s] = exp2f(a2[s] * dt) * h[s] + Bv[s] * u;
  }

  const long cb = (long)(b * NC + c);
#pragma unroll
  for (int s = 0; s < 16; s++) hend[(cb * 16 + s) * INNER + ch] = h[s];
  dtsum[cb * INNER + ch] = dts;
}

// ---------------------------------------------------------------------------
// 6b. combine: sequential over NC chunks; rewrites hend -> h_start in place.
// ---------------------------------------------------------------------------
__global__ __launch_bounds__(256) void scan_combine_kernel(
    float* __restrict__ hio, const float* __restrict__ dtsum,
    const float* __restrict__ A2) {
  const int idx = blockIdx.x * 256 + threadIdx.x;  // < BATCH*16*INNER
  const int ch = idx & (INNER - 1);
  const int s = (idx >> 11) & 15;
  const int b = idx >> 15;
  const float a2 = A2[(long)ch * 16 + s];
  float H = 0.0f;
  for (int c = 0; c < NC; c++) {
    const long cb = (long)(b * NC + c);
    const long o = (cb * 16 + s) * INNER + ch;
    const float he = hio[o];
    const float ds = dtsum[cb * INNER + ch];
    hio[o] = H;  // h_start for chunk c
    H = exp2f(a2 * ds) * H + he;
  }
}

// ---------------------------------------------------------------------------
// 6c. scan pass 3: re-scan chunk from true h_start; y = (C.h + D*xc)*silu(res)
// ---------------------------------------------------------------------------
__global__ __launch_bounds__(256) void scan_pass3_kernel(
    const float* __restrict__ dtm, const float* __restrict__ bc,
    const bf16* __restrict__ xc, const bf16* __restrict__ rs,
    const float* __restrict__ A2, const float* __restrict__ Dv,
    const float* __restrict__ hstart, bf16* __restrict__ y) {
  const int ch = blockIdx.x * 256 + threadIdx.x;
  const int c = blockIdx.y;
  const int b = blockIdx.z;
  const long row0 = (long)b * SEQ + (long)c * CHUNK;

  float a2[16];
#pragma unroll
  for (int q = 0; q < 4; q++) {
    const float4 t = ((const float4*)(A2 + (long)ch * 16))[q];
    a2[q * 4 + 0] = t.x; a2[q * 4 + 1] = t.y;
    a2[q * 4 + 2] = t.z; a2[q * 4 + 3] = t.w;
  }
  const float d = Dv[ch];
  const long cb = (long)(b * NC + c);
  float h[16];
#pragma unroll
  for (int s = 0; s < 16; s++) h[s] = hstart[(cb * 16 + s) * INNER + ch];

  float dtq[PF2], xcq[PF2], rsq[PF2];
#pragma unroll
  for (int p = 0; p < PF2; p++) {
    const long r2 = row0 + p;
    dtq[p] = dtm[r2 * INNER + ch];
    xcq[p] = (float)xc[r2 * INNER + ch];
    rsq[p] = (float)rs[r2 * INNER + ch];
  }
  for (int l0 = 0; l0 <= CHUNK - 2 * PF2; l0 += PF2) {
#pragma unroll
    for (int p = 0; p < PF2; p++) {
      const float dt = dtq[p], xcv = xcq[p], rsv = rsq[p];
      const long rp = row0 + l0 + p + PF2;
      dtq[p] = dtm[rp * INNER + ch];
      xcq[p] = (float)xc[rp * INNER + ch];
      rsq[p] = (float)rs[rp * INNER + ch];
      const long r = row0 + l0 + p;
      float Bv[16], Cv[16];
#pragma unroll
      for (int k = 0; k < 16; k++) Bv[k] = bc[r * 32 + k];
#pragma unroll
      for (int k = 0; k < 16; k++) Cv[k] = bc[r * 32 + 16 + k];
      const float u = dt * xcv;
      float yv = d * xcv;
#pragma unroll
      for (int s = 0; s < 16; s++) {
        h[s] = exp2f(a2[s] * dt) * h[s] + Bv[s] * u;
        yv += h[s] * Cv[s];
      }
      y[r * INNER + ch] = (bf16)(yv * rsv);
    }
  }
#pragma unroll
  for (int p = 0; p < PF2; p++) {
    const float dt = dtq[p], xcv = xcq[p], rsv = rsq[p];
    const long r = row0 + CHUNK - PF2 + p;
    float Bv[16], Cv[16];
#pragma unroll
    for (int k = 0; k < 16; k++) Bv[k] = bc[r * 32 + k];
#pragma unroll
    for (int k = 0; k < 16; k++) Cv[k] = bc[r * 32 + 16 + k];
    const float u = dt * xcv;
    float yv = d * xcv;
#pragma unroll
    for (int s = 0; s < 16; s++) {
      h[s] = exp2f(a2[s] * dt) * h[s] + Bv[s] * u;
      yv += h[s] * Cv[s];
    }
    y[r * INNER + ch] = (bf16)(yv * rsv);
  }
}

// ---------------------------------------------------------------------------
// launch
// ---------------------------------------------------------------------------
extern "C" void kernel_launch(void* const* d_in, const int* in_sizes, int n_in,
                              void* d_out, int out_size, void* d_ws,
                              size_t ws_size, hipStream_t stream) {
  (void)in_sizes; (void)n_in; (void)out_size;
  const float* x      = (const float*)d_in[0];
  const float* w_norm = (const float*)d_in[1];
  const float* W_in   = (const float*)d_in[2];
  const float* conv_w = (const float*)d_in[3];
  const float* conv_b = (const float*)d_in[4];
  const float* W_dt   = (const float*)d_in[5];
  const float* b_dt   = (const float*)d_in[6];
  const float* W_B    = (const float*)d_in[7];
  const float* W_C    = (const float*)d_in[8];
  const float* A_log  = (const float*)d_in[9];
  const float* Dv     = (const float*)d_in[10];
  const float* W_out  = (const float*)d_in[11];
  float* out = (float*)d_out;

  // ---- workspace layout (lifetime-aliased, 173.625 MiB total) -------------
  const size_t MB = 1024ull * 1024ull;
  char* base = (char*)d_ws;
  bf16*  xnorm  = (bf16*)(base + 0);          // 16 MiB [rmsnorm -> gemm1]
  bf16*  win_b  = (bf16*)(base + 16 * MB);    //  8 MiB [pack -> gemm1]
  bf16*  xin_b  = (bf16*)(base + 24 * MB);    // 32 MiB [gemm1 -> conv]
  float* dtm    = (float*)(base + 0);         // 64 MiB [gemm2 -> scan] ALIAS
  float* bcm    = (float*)(base + 64 * MB);   //  1 MiB [gemm2 -> scan]
  bf16*  res_b  = (bf16*)(base + 65 * MB);    // 32 MiB [gemm1 -> scan]
  bf16*  xc_b   = (bf16*)(base + 97 * MB);    // 32 MiB [conv -> gemm2, scan]
  bf16*  wdtbcb = (bf16*)(base + 129 * MB);   // 8.5 MiB [pack -> gemm2]
  // chunk state aliases wdtbcb (dead after gemm2): 8 MiB hend + 0.5 MiB dtsum
  float* hend   = (float*)(base + 129 * MB);                 // 8 MiB
  float* dtsum  = (float*)(base + 137 * MB);                 // 0.5 MiB
  char*  p2     = base + 129 * MB + (size_t)NBC * INNER * 2;
  bf16*  wout_b = (bf16*)p2;                  //  4 MiB [pack -> gemm3]
  float* A2     = (float*)(p2 + (size_t)DIM * INNER * 2);  // 128 KiB
  bf16*  yb     = (bf16*)(p2 + (size_t)DIM * INNER * 2 +
                          (size_t)INNER * STATE * 4);      // 32 MiB [scan->g3]
  const size_t NEEDED = (size_t)((char*)yb - base) + (size_t)ROWS * INNER * 2;

  if (ws_size < NEEDED) {  // diagnostic: fail with absmax == ws_size
    ws_report_kernel<<<1, 64, 0, stream>>>(out, (float)ws_size, (float)NEEDED);
    return;
  }

  // 1. rmsnorm -> xnorm bf16
  rmsnorm_kernel<<<ROWS, 256, 0, stream>>>(x, w_norm, xnorm);

  // 2. weight packs
  cvt_bf16_kernel<<<(N1 * DIM) / 256, 256, 0, stream>>>(W_in, win_b, N1 * DIM);
  build_wdtbc_kernel<<<(NBC * INNER) / 256, 256, 0, stream>>>(W_dt, W_B, W_C,
                                                              wdtbcb);
  cvt_bf16_kernel<<<(DIM * INNER) / 256, 256, 0, stream>>>(W_out, wout_b,
                                                           DIM * INNER);
  build_a2_kernel<<<(INNER * STATE) / 256, 256, 0, stream>>>(A_log, A2);

  // 3. GEMM1 (256sq 8-phase): xnorm(8192x1024) @ W_in^T(4096x1024)
  //    -> xin_b | silu->res_b.  grid 32x16=512 (%8==0)
  gemm256_kernel<2, 1024, 16><<<512, 512, 0, stream>>>(
      xnorm, win_b, nullptr, nullptr, xin_b, res_b, nullptr, N1 - 1);

  // 4. conv + silu -> xc_b
  conv_silu_kernel<<<dim3(INNER / 256, ROWS), 256, 0, stream>>>(
      xin_b, conv_w, conv_b, xc_b);

  // 5. GEMM2 (256sq 8-phase): xc_b(8192x2048) @ [Wdt;WB;WC]^T -> dtm | bcm
  //    N padded to 9 tiles (2304); pad tile clamps B rows to zero row 2175.
  //    grid 32x9=288 (%8==0)
  gemm256_kernel<1, 2048, 9><<<288, 512, 0, stream>>>(
      xc_b, wdtbcb, dtm, bcm, nullptr, nullptr, b_dt, NBC - 1);

  // 6. chunked scan: pass1 -> combine -> pass3
  scan_pass1_kernel<<<dim3(INNER / 256, NC, BATCH), 256, 0, stream>>>(
      dtm, bcm, xc_b, A2, hend, dtsum);
  scan_combine_kernel<<<(BATCH * 16 * INNER) / 256, 256, 0, stream>>>(
      hend, dtsum, A2);
  scan_pass3_kernel<<<dim3(INNER / 256, NC, BATCH), 256, 0, stream>>>(
      dtm, bcm, xc_b, res_b, A2, Dv, hend, yb);

  // 7. GEMM3: yb(8192x2048) @ W_out^T(1024x2048) -> out f32
  gemm_bf16_kernel<0><<<(DIM / 128) * (ROWS / 128), 256, 0, stream>>>(
      yb, wout_b, out, nullptr, nullptr, nullptr, nullptr, DIM / 128, DIM,
      INNER);
}